// Round 2
// 126.845 us; speedup vs baseline: 1.0369x; 1.0369x over previous
//
#include <hip/hip_runtime.h>

// ---------------------------------------------------------------------------
// MaskAttentionHead v15: HW bf16 conversion via __builtin_convertvector.
//  v14 post-mortem: hand-written v_cvt_pk_bf16_f32 inline asm broke
//  correctness (O(1) error consistent with pairwise row swaps in the
//  epilogue packing -> suspect operand/half-order semantics). v15 expresses
//  every f32->bf16 as fptrunc via __builtin_convertvector(float4 -> bf16x4):
//  element order + RNE guaranteed by LLVM; gfx950 ISel picks the native
//  packed cvt. log2e folding reverted (0.125 scale + __expf, 2 instrs).
//  Structure (grids, LDS swizzle, fragment layouts, flash schedule) = v13.
// ws: WF 384KB | Qg 2MB | KF 2MB | VF 2MB  (~6.7MB)
// ---------------------------------------------------------------------------

typedef __attribute__((ext_vector_type(8))) short v8s;           // 8 x bf16 (MFMA operand)
typedef __attribute__((ext_vector_type(4))) float v4f;           // MFMA 16x16 C/D
typedef __attribute__((ext_vector_type(4))) float f4;            // 4 x f32
typedef __attribute__((ext_vector_type(8))) float f8;            // 8 x f32
typedef __attribute__((ext_vector_type(4))) __bf16 bf4;          // 4 x bf16
typedef __attribute__((ext_vector_type(8))) __bf16 bf8;          // 8 x bf16
typedef __attribute__((ext_vector_type(4))) unsigned short u4;   // 4 x u16

// f32x4 -> bf16x4 (RNE, HW packed cvt on gfx950), as raw u16 lanes.
static __device__ __forceinline__ u4 cvt4(f4 v) {
  return __builtin_bit_cast(u4, __builtin_convertvector(v, bf4));
}

// f32x8 -> bf16x8 as an MFMA A/B operand.
static __device__ __forceinline__ v8s cvt8(f4 lo, f4 hi) {
  f8 ff = __builtin_shufflevector(lo, hi, 0, 1, 2, 3, 4, 5, 6, 7);
  return __builtin_bit_cast(v8s, __builtin_convertvector(ff, bf8));
}

// async 16B/lane global->LDS DMA: dst wave-uniform base, lane i -> dst+i*16.
static __device__ __forceinline__ void dma16(const void* src, void* dst) {
  __builtin_amdgcn_global_load_lds(
      (const __attribute__((address_space(1))) void*)src,
      (__attribute__((address_space(3))) void*)dst, 16, 0, 0);
}

// --- kernel 1: pack weights into WF ----------------------------------------
// WF chunk (g*12+nt)*512 (+lane*8) = B-fragment for 32-K group g, n-tile nt:
// lane(quad,colid) holds W[n=nt*16+colid][k=g*32+quad*8+j].  1/8 folded in Wq.
__global__ __launch_bounds__(256) void pack_w(const float* __restrict__ Wq,
                                              const float* __restrict__ Wk,
                                              const float* __restrict__ Wv,
                                              unsigned short* __restrict__ WF) {
  int idx = (blockIdx.x * 256 + threadIdx.x) * 4;  // 192*1024 total
  int row = idx >> 10;
  int k   = idx & 1023;
  const float* src;
  float scale;
  if (row < 64)       { src = Wq + row * 1024 + k;         scale = 0.125f; }
  else if (row < 128) { src = Wk + (row - 64) * 1024 + k;  scale = 1.0f;   }
  else                { src = Wv + (row - 128) * 1024 + k; scale = 1.0f;   }
  f4 f = *(const f4*)src;
  u4 o = cvt4(f * scale);
  size_t off = ((size_t)(k >> 5) * 12 + (row >> 4)) * 512 +
               (((k >> 3) & 3) * 16 + (row & 15)) * 8 + (k & 7);
  *(u4*)(WF + off) = o;
}

// --- kernel 2: QKV projection ----------------------------------------------
// 512 blocks x 256 threads, 32 rows/block. K in 8 steps of 128 (= 32 16-B
// units/row/step). LDS unit (r, su) at byte r*512 + su*16 holds global unit
// u = su ^ (r&7)  (XOR stays inside a 128-B line -> DMA coalescing intact,
// ds_read banks spread). Wave wv stages chunks j in [wv*4,wv*4+4) (chunk j =
// rows {2j,2j+1}); computes n-tiles {wv*3..wv*3+2} for both m-groups.
__global__ __launch_bounds__(256) void qkv(const float* __restrict__ x,
                                           const unsigned short* __restrict__ WF,
                                           unsigned short* __restrict__ Qg,
                                           unsigned short* __restrict__ KF,
                                           unsigned short* __restrict__ VF) {
  __shared__ alignas(16) char xs[2][16384];
  const int tid   = threadIdx.x;
  const int lane  = tid & 63;
  const int wv    = tid >> 6;        // 0..3
  const int quad  = lane >> 4;
  const int colid = lane & 15;
  const int row0  = blockIdx.x * 32;

  const char* xB = (const char*)x;
  const unsigned short* wf = WF + lane * 8;

  // per-lane DMA source pieces: rloc = 2j + (lane>>5), su = lane&31
  const int rpar = lane >> 5;          // which of the chunk's two rows
  const int su_l = lane & 31;          // stored unit
  const int c7   = colid & 7;

  v4f acc[6];   // [mg][ntl] = acc[mg*3+ntl]
#pragma unroll
  for (int i = 0; i < 6; i++) acc[i] = (v4f){0.f, 0.f, 0.f, 0.f};

  auto stage = [&](int kt, int slot) {
#pragma unroll
    for (int i = 0; i < 4; i++) {
      int j    = wv * 4 + i;           // chunk = rows {2j, 2j+1}
      int rloc = 2 * j + rpar;
      int u    = su_l ^ (rloc & 7);    // in-line XOR swizzle
      const char* src = xB + (size_t)(row0 + rloc) * 4096 + kt * 512 + u * 16;
      dma16(src, &xs[slot][j * 1024]);
    }
  };

  stage(0, 0);

  for (int kt = 0; kt < 8; kt++) {
    const int slot = kt & 1;
    __syncthreads();                       // drain stage kt
    if (kt < 7) stage(kt + 1, slot ^ 1);   // overlaps compute kt
#pragma unroll
    for (int s = 0; s < 4; s++) {
      const int g = kt * 4 + s;
      v8s bw[3];
#pragma unroll
      for (int ntl = 0; ntl < 3; ntl++)
        bw[ntl] = *(const v8s*)(wf + ((size_t)g * 12 + wv * 3 + ntl) * 512);
#pragma unroll
      for (int mg = 0; mg < 2; mg++) {
        const int rr = mg * 16 + colid;
        const int u0 = s * 8 + quad * 2;
        f4 f0 = *(const f4*)(&xs[slot][rr * 512 + (u0 ^ c7) * 16]);
        f4 f1 = *(const f4*)(&xs[slot][rr * 512 + ((u0 + 1) ^ c7) * 16]);
        v8s a = cvt8(f0, f1);
#pragma unroll
        for (int ntl = 0; ntl < 3; ntl++)
          acc[mg * 3 + ntl] =
              __builtin_amdgcn_mfma_f32_16x16x32_bf16(a, bw[ntl], acc[mg * 3 + ntl], 0, 0, 0);
      }
    }
  }

  // epilogue: wave wv stores n-tiles wv*3..wv*3+2 for both m-groups
#pragma unroll
  for (int ntl = 0; ntl < 3; ntl++) {
    const int nt = wv * 3 + ntl;
#pragma unroll
    for (int mg = 0; mg < 2; mg++) {
      const int trow_base = row0 + mg * 16 + quad * 4;
      const v4f av = acc[mg * 3 + ntl];
      u4 cc = cvt4((f4){av[0], av[1], av[2], av[3]});
      if (nt < 4) {
#pragma unroll
        for (int r = 0; r < 4; r++)
          Qg[(size_t)(trow_base + r) * 64 + nt * 16 + colid] = cc[r];
      } else if (nt < 8) {
        int half = (nt - 4) >> 1;
        int q_f  = ((nt - 4) * 2 + (colid >> 3)) & 3;
        int j    = colid & 7;
#pragma unroll
        for (int r = 0; r < 4; r++) {
          int t  = trow_base + r;
          int b  = t >> 12, tl = t & 4095;
          int si = tl >> 6, sl = tl & 63;
          KF[((size_t)(b * 64 + si) * 8 + (sl >> 4) * 2 + half) * 512 +
             (q_f * 16 + (sl & 15)) * 8 + j] = cc[r];
        }
      } else {
#pragma unroll
        for (int r = 0; r < 4; r++) {
          int t  = trow_base + r;
          int b  = t >> 12, tl = t & 4095;
          int si = tl >> 6;
          int half = (tl >> 5) & 1, q_f = (tl >> 3) & 3, j = tl & 7;
          VF[((size_t)(b * 64 + si) * 8 + (nt - 8) * 2 + half) * 512 +
             (q_f * 16 + colid) * 8 + j] = cc[r];
        }
      }
    }
  }
}

// --- kernel 3: causal flash, BM=32/wave, 4-way si-split ---------------------
__global__ __launch_bounds__(256, 2) void flash(const unsigned short* __restrict__ Qg,
                                                const unsigned short* __restrict__ KF,
                                                const unsigned short* __restrict__ VF,
                                                float* __restrict__ out) {
  __shared__ alignas(16) char smem[4 * 32 * 68 * 4 + 4 * 32 * 4];
  unsigned short* pl = (unsigned short*)smem;
  float* redf = (float*)smem;
  float* lred = (float*)(smem + 4 * 32 * 68 * 4);

  const int tid   = threadIdx.x;
  const int lane  = tid & 63;
  const int wv    = tid >> 6;               // si-split id 0..3
  const int quad  = lane >> 4;
  const int colid = lane & 15;
  const int qt32  = 127 - (int)(blockIdx.x >> 2);   // longest-first
  const int b     = blockIdx.x & 3;
  const int bT    = b * 4096;
  const int row00 = qt32 * 32;
  const int qimax = (row00 + 31) >> 6;

  v8s qf[2][2];
#pragma unroll
  for (int mt = 0; mt < 2; mt++) {
    const unsigned short* qrow =
        Qg + (size_t)(bT + row00 + mt * 16 + colid) * 64 + quad * 8;
    qf[mt][0] = *(const v8s*)(qrow);
    qf[mt][1] = *(const v8s*)(qrow + 32);
  }

  v8s ones;
#pragma unroll
  for (int j = 0; j < 8; j++) ones[j] = (short)0x3F80;  // bf16 1.0

  v4f o[2][4];
#pragma unroll
  for (int mt = 0; mt < 2; mt++)
#pragma unroll
    for (int i = 0; i < 4; i++) o[mt][i] = (v4f){0.f, 0.f, 0.f, 0.f};
  v4f lac[2];
  lac[0] = (v4f){0.f, 0.f, 0.f, 0.f};
  lac[1] = (v4f){0.f, 0.f, 0.f, 0.f};

  const unsigned short* kb0 = KF + (size_t)b * 64 * 4096 + lane * 8;
  const unsigned short* vb0 = VF + (size_t)b * 64 * 4096 + lane * 8;

  for (int si = wv; si <= qimax; si += 4) {
    const unsigned short* ktile = kb0 + (size_t)si * 4096;
    const unsigned short* vtile = vb0 + (size_t)si * 4096;
    v8s ck[8], cv[8];
#pragma unroll
    for (int c = 0; c < 8; c++) ck[c] = *(const v8s*)(ktile + (size_t)c * 512);
#pragma unroll
    for (int c = 0; c < 8; c++) cv[c] = *(const v8s*)(vtile + (size_t)c * 512);

#pragma unroll
    for (int mt = 0; mt < 2; mt++) {
      v4f s[4];
#pragma unroll
      for (int i = 0; i < 4; i++) s[i] = (v4f){0.f, 0.f, 0.f, 0.f};
#pragma unroll
      for (int nt = 0; nt < 4; nt++) {
        s[nt] = __builtin_amdgcn_mfma_f32_16x16x32_bf16(qf[mt][0], ck[2 * nt], s[nt], 0, 0, 0);
        s[nt] = __builtin_amdgcn_mfma_f32_16x16x32_bf16(qf[mt][1], ck[2 * nt + 1], s[nt], 0, 0, 0);
      }

      if (si == qimax) {    // diagonal-containing tile: causal mask
        int rowb = row00 + mt * 16 + quad * 4;
        int colb = si * 64;
#pragma unroll
        for (int nt = 0; nt < 4; nt++)
#pragma unroll
          for (int r = 0; r < 4; r++)
            if (colb + nt * 16 + colid > rowb + r) s[nt][r] = -1e30f;
      }

      unsigned short* pw = pl + (wv * 2 + mt) * (16 * 72);
#pragma unroll
      for (int nt = 0; nt < 4; nt++) {
        f4 ev = {__expf(s[nt][0]), __expf(s[nt][1]),
                 __expf(s[nt][2]), __expf(s[nt][3])};
        u4 p = cvt4(ev);
        unsigned short* pb = pw + quad * 4 * 72 + nt * 16 + colid;
        pb[0]   = p[0];
        pb[72]  = p[1];
        pb[144] = p[2];
        pb[216] = p[3];
      }
    }

#pragma unroll
    for (int mt = 0; mt < 2; mt++) {
      unsigned short* pw = pl + (wv * 2 + mt) * (16 * 72);
#pragma unroll
      for (int ks = 0; ks < 64; ks += 32) {
        v8s af = *(const v8s*)(&pw[colid * 72 + ks + quad * 8]);
        lac[mt] = __builtin_amdgcn_mfma_f32_16x16x32_bf16(af, ones, lac[mt], 0, 0, 0);
#pragma unroll
        for (int nt = 0; nt < 4; nt++)
          o[mt][nt] = __builtin_amdgcn_mfma_f32_16x16x32_bf16(
              af, cv[2 * nt + (ks >> 5)], o[mt][nt], 0, 0, 0);
      }
    }
  }

  __syncthreads();
#pragma unroll
  for (int mt = 0; mt < 2; mt++) {
#pragma unroll
    for (int nt = 0; nt < 4; nt++)
#pragma unroll
      for (int r = 0; r < 4; r++)
        redf[(wv * 32 + mt * 16 + quad * 4 + r) * 68 + nt * 16 + colid] = o[mt][nt][r];
    if (colid == 0) {
#pragma unroll
      for (int r = 0; r < 4; r++)
        lred[wv * 32 + mt * 16 + quad * 4 + r] = lac[mt][r];
    }
  }
  __syncthreads();

  {
    int col = tid & 63;
    int r0  = tid >> 6;
#pragma unroll
    for (int rr = 0; rr < 8; rr++) {
      int row = r0 * 8 + rr;
      float sum = 0.f, lsum = 0.f;
#pragma unroll
      for (int w = 0; w < 4; w++) {
        sum  += redf[(w * 32 + row) * 68 + col];
        lsum += lred[w * 32 + row];
      }
      out[(size_t)(bT + row00 + row) * 64 + col] = sum / lsum;
    }
  }
}

extern "C" void kernel_launch(void* const* d_in, const int* in_sizes, int n_in,
                              void* d_out, int out_size, void* d_ws, size_t ws_size,
                              hipStream_t stream) {
  const float* x  = (const float*)d_in[0];
  const float* Wq = (const float*)d_in[1];
  const float* Wk = (const float*)d_in[2];
  const float* Wv = (const float*)d_in[3];
  float* out = (float*)d_out;

  unsigned short* WF = (unsigned short*)d_ws;          // 192*1024
  unsigned short* Qg = WF + 192 * 1024;                // 16384*64 row-major
  unsigned short* KF = Qg + 16384 * 64;                // fragment-linear
  unsigned short* VF = KF + 16384 * 64;                // fragment-linear

  hipLaunchKernelGGL(pack_w, dim3(192), dim3(256), 0, stream, Wq, Wk, Wv, WF);
  hipLaunchKernelGGL(qkv, dim3(512), dim3(256), 0, stream, x, WF, Qg, KF, VF);
  hipLaunchKernelGGL(flash, dim3(512), dim3(256), 0, stream, Qg, KF, VF, out);
}